// Round 2
// baseline (190.167 us; speedup 1.0000x reference)
//
#include <hip/hip_runtime.h>
#include <hip/hip_bf16.h>
#include <cstdint>
#include <cstddef>

typedef __attribute__((ext_vector_type(8))) short bf16x8;
typedef __attribute__((ext_vector_type(4))) float f32x4;
typedef unsigned short u16;
typedef unsigned int u32;

#define DEV static __device__ __forceinline__

constexpr int Sc = 1024, DMc = 1024, Hc = 16, DKc = 64;

DEV u16 f2bf(float f) {
  u32 u = __float_as_uint(f);
  return (u16)((u + 0x7FFFu + ((u >> 16) & 1u)) >> 16);
}
DEV float bf2f(u16 h) { return __uint_as_float(((u32)h) << 16); }

// async global->LDS, 16B per lane, dest = wave-uniform base + lane*16
#define GLDS16(g, l)                                                        \
  __builtin_amdgcn_global_load_lds(                                         \
      (const __attribute__((address_space(1))) void*)(g),                   \
      (__attribute__((address_space(3))) void*)(l), 16, 0, 0)

// ---------------- f32 -> bf16 conversion ----------------
struct CvtJob { const float* in; u16* out; int n; };
struct CvtArgs { CvtJob j[8]; };

__global__ __launch_bounds__(256) void cvt_kernel(CvtArgs a) {
  CvtJob job = a.j[blockIdx.y];
  int i = (int)(blockIdx.x * 256 + threadIdx.x) * 4;
  if (i >= job.n) return;
  float4 v = *(const float4*)(job.in + i);
  ushort4 o;
  o.x = f2bf(v.x); o.y = f2bf(v.y); o.z = f2bf(v.z); o.w = f2bf(v.w);
  *(ushort4*)(job.out + i) = o;
}

// ---------------- GEMM: C = A(MxK) * W(NxK)^T + bias ----------------
// MODE 0: bias[n]; write bf16 head-split [b,h,s,d]   (m=b*S+s, n=h*64+d)
// MODE 1: bias[n]; write f32 row-major [m][n]
// MODE 2: bias[m]; write bf16 V^T [bh][d][s]         (m=h*64+d, n=b*S+s)
struct GemmJob { const u16* A; const u16* W; const float* bias; void* out; };
struct GemmJobs { GemmJob p[3]; };

template<int MODE>
__global__ __launch_bounds__(256) void gemm_bt(GemmJobs G, int K) {
  GemmJob P = G.p[blockIdx.z];
  __shared__ __align__(16) u16 sA[128 * 64];
  __shared__ __align__(16) u16 sB[128 * 64];
  const int tid = threadIdx.x, lane = tid & 63, w = tid >> 6;
  const int cl = lane & 15, rg = lane >> 4;
  const int m0 = blockIdx.y * 128, n0 = blockIdx.x * 128;
  const int wm = (w >> 1) * 64, wn = (w & 1) * 64;
  const int srow = w * 32 + (lane >> 3);  // staging: row within tile (chunk adds i*8)
  const int scol = (lane & 7) * 8;
  f32x4 acc[4][4] = {};

  for (int k0 = 0; k0 < K; k0 += 64) {
    __syncthreads();
    #pragma unroll
    for (int i = 0; i < 4; ++i) {
      GLDS16(P.A + (size_t)(m0 + srow + i * 8) * K + k0 + scol, &sA[(w * 32 + i * 8) * 64]);
      GLDS16(P.W + (size_t)(n0 + srow + i * 8) * K + k0 + scol, &sB[(w * 32 + i * 8) * 64]);
    }
    __syncthreads();
    #pragma unroll
    for (int kk = 0; kk < 2; ++kk) {
      bf16x8 af[4], bfr[4];
      #pragma unroll
      for (int mi = 0; mi < 4; ++mi)
        af[mi] = *(const bf16x8*)&sA[(wm + mi * 16 + cl) * 64 + kk * 32 + rg * 8];
      #pragma unroll
      for (int ni = 0; ni < 4; ++ni)
        bfr[ni] = *(const bf16x8*)&sB[(wn + ni * 16 + cl) * 64 + kk * 32 + rg * 8];
      #pragma unroll
      for (int mi = 0; mi < 4; ++mi)
        #pragma unroll
        for (int ni = 0; ni < 4; ++ni)
          acc[mi][ni] = __builtin_amdgcn_mfma_f32_16x16x32_bf16(af[mi], bfr[ni], acc[mi][ni], 0, 0, 0);
    }
  }
  #pragma unroll
  for (int mi = 0; mi < 4; ++mi) {
    #pragma unroll
    for (int ni = 0; ni < 4; ++ni) {
      #pragma unroll
      for (int j = 0; j < 4; ++j) {
        int m = m0 + wm + mi * 16 + rg * 4 + j;
        int n = n0 + wn + ni * 16 + cl;
        if (MODE == 0) {
          float v = acc[mi][ni][j] + P.bias[n];
          int b = m >> 10, s = m & 1023, h = n >> 6, d = n & 63;
          ((u16*)P.out)[((size_t)(b * Hc + h) * Sc + s) * DKc + d] = f2bf(v);
        } else if (MODE == 1) {
          float v = acc[mi][ni][j] + P.bias[n];
          ((float*)P.out)[(size_t)m * DMc + n] = v;
        } else {
          float v = acc[mi][ni][j] + P.bias[m];
          // m = h*64+d (W row), n = b*1024+s (X row) -> vt[bh][d][s]
          ((u16*)P.out)[(((size_t)(n >> 10) * Hc + (m >> 6)) * DKc + (m & 63)) * Sc + (n & 1023)] = f2bf(v);
        }
      }
    }
  }
}

// ---------------- fused relative attention ----------------
// grid: 2048 flat blocks (bh = id&31, qt = id>>5), block 128 (2 waves)
// wave w handles 16 q-rows x k-half w; merge partials at the end.
__global__ __launch_bounds__(128, 4) void attn_rel(
    const u16* __restrict__ qg, const u16* __restrict__ kg,
    const u16* __restrict__ vtg, const u16* __restrict__ erg,
    u16* __restrict__ og) {
  __shared__ u16 sT[2][16 * 84];               // per-wave T (bf16)
  __shared__ __align__(16) u16 sP[2][16 * 72]; // per-wave P (bf16)
  __shared__ __align__(16) float sO[16 * 64];  // wave1 partial O
  __shared__ float sm[16], sl[16];

  const int tid = threadIdx.x, lane = tid & 63, w = tid >> 6;
  const int cl = lane & 15, rg = lane >> 4;
  const int bh = blockIdx.x & 31, qt = blockIdx.x >> 5;
  const int q0 = qt * 16;

  bf16x8 qf0, qf1;
  {
    const u16* qp = qg + ((size_t)bh * Sc + q0 + cl) * DKc + rg * 8;
    qf0 = *(const bf16x8*)qp;
    qf1 = *(const bf16x8*)(qp + 32);
  }
  f32x4 oacc[4] = {};
  float mrow[4] = {-1e30f, -1e30f, -1e30f, -1e30f};
  float lrow[4] = {0.f, 0.f, 0.f, 0.f};
  u16* Tw = sT[w];
  u16* Pw = sP[w];

  for (int t = 0; t < 8; ++t) {
    const int k0 = (w * 8 + t) * 64;
    // QK^T: 16x64 scores (fragments straight from global; L2-resident)
    f32x4 sc4[4];
    #pragma unroll
    for (int nc = 0; nc < 4; ++nc) {
      const u16* kp = kg + ((size_t)bh * Sc + k0 + nc * 16 + cl) * DKc + rg * 8;
      bf16x8 b0 = *(const bf16x8*)kp;
      bf16x8 b1 = *(const bf16x8*)(kp + 32);
      f32x4 a = {};
      a = __builtin_amdgcn_mfma_f32_16x16x32_bf16(qf0, b0, a, 0, 0, 0);
      a = __builtin_amdgcn_mfma_f32_16x16x32_bf16(qf1, b1, a, 0, 0, 0);
      sc4[nc] = a;
    }
    // T = Q . Er_window^T  (window rows r0..r0+79, all in [0,2047])
    const int r0 = q0 - k0 + 960;
    #pragma unroll
    for (int rc = 0; rc < 5; ++rc) {
      const u16* ep = erg + ((size_t)(r0 + rc * 16 + cl)) * DKc + rg * 8;
      bf16x8 b0 = *(const bf16x8*)ep;
      bf16x8 b1 = *(const bf16x8*)(ep + 32);
      f32x4 a = {};
      a = __builtin_amdgcn_mfma_f32_16x16x32_bf16(qf0, b0, a, 0, 0, 0);
      a = __builtin_amdgcn_mfma_f32_16x16x32_bf16(qf1, b1, a, 0, 0, 0);
      #pragma unroll
      for (int j = 0; j < 4; ++j)
        Tw[(rg * 4 + j) * 84 + rc * 16 + cl] = f2bf(a[j]);
    }
    // gather relative term + online softmax
    #pragma unroll
    for (int j = 0; j < 4; ++j) {
      const int qi = rg * 4 + j;
      float sv[4];
      float mx = -1e30f;
      #pragma unroll
      for (int nc = 0; nc < 4; ++nc) {
        int r = qi + 63 - (nc * 16 + cl);  // in [0, 78]
        float tval = bf2f(Tw[qi * 84 + r]);
        float s = (sc4[nc][j] + tval) * 0.125f;
        sv[nc] = s;
        mx = fmaxf(mx, s);
      }
      #pragma unroll
      for (int off = 1; off < 16; off <<= 1)
        mx = fmaxf(mx, __shfl_xor(mx, off));
      float mnew = fmaxf(mrow[j], mx);
      float alpha = __expf(mrow[j] - mnew);
      mrow[j] = mnew;
      float rs = 0.f;
      #pragma unroll
      for (int nc = 0; nc < 4; ++nc) {
        float pv = __expf(sv[nc] - mnew);
        rs += pv;
        Pw[qi * 72 + nc * 16 + cl] = f2bf(pv);
      }
      #pragma unroll
      for (int off = 1; off < 16; off <<= 1)
        rs += __shfl_xor(rs, off);
      lrow[j] = lrow[j] * alpha + rs;
      #pragma unroll
      for (int dc = 0; dc < 4; ++dc) oacc[dc][j] *= alpha;
    }
    // PV: fragments of V^T straight from global
    bf16x8 pa0 = *(const bf16x8*)&Pw[cl * 72 + rg * 8];
    bf16x8 pa1 = *(const bf16x8*)&Pw[cl * 72 + 32 + rg * 8];
    #pragma unroll
    for (int dc = 0; dc < 4; ++dc) {
      const u16* vp = vtg + ((size_t)bh * DKc + dc * 16 + cl) * Sc + k0 + rg * 8;
      bf16x8 b0 = *(const bf16x8*)vp;
      bf16x8 b1 = *(const bf16x8*)(vp + 32);
      oacc[dc] = __builtin_amdgcn_mfma_f32_16x16x32_bf16(pa0, b0, oacc[dc], 0, 0, 0);
      oacc[dc] = __builtin_amdgcn_mfma_f32_16x16x32_bf16(pa1, b1, oacc[dc], 0, 0, 0);
    }
  }
  // merge the two k-halves
  if (w == 1) {
    #pragma unroll
    for (int dc = 0; dc < 4; ++dc)
      #pragma unroll
      for (int j = 0; j < 4; ++j)
        sO[(rg * 4 + j) * 64 + dc * 16 + cl] = oacc[dc][j];
    if (cl == 0) {
      #pragma unroll
      for (int j = 0; j < 4; ++j) {
        sm[rg * 4 + j] = mrow[j];
        sl[rg * 4 + j] = lrow[j];
      }
    }
  }
  __syncthreads();
  if (w == 0) {
    const int b = bh >> 4, h = bh & 15;
    float a0[4], a1[4], rinv[4];
    #pragma unroll
    for (int j = 0; j < 4; ++j) {
      float m1 = sm[rg * 4 + j], l1 = sl[rg * 4 + j];
      float mf = fmaxf(mrow[j], m1);
      a0[j] = __expf(mrow[j] - mf);
      a1[j] = __expf(m1 - mf);
      rinv[j] = 1.0f / (lrow[j] * a0[j] + l1 * a1[j]);
    }
    #pragma unroll
    for (int dc = 0; dc < 4; ++dc) {
      #pragma unroll
      for (int j = 0; j < 4; ++j) {
        int qi = rg * 4 + j;
        float v = (oacc[dc][j] * a0[j] + sO[qi * 64 + dc * 16 + cl] * a1[j]) * rinv[j];
        og[((size_t)(b * Sc + q0 + qi)) * DMc + h * DKc + dc * 16 + cl] = f2bf(v);
      }
    }
  }
}

// ---------------- host ----------------
extern "C" void kernel_launch(void* const* d_in, const int* in_sizes, int n_in,
                              void* d_out, int out_size, void* d_ws, size_t ws_size,
                              hipStream_t stream) {
  (void)in_sizes; (void)n_in; (void)out_size; (void)ws_size;
  const float* query = (const float*)d_in[0];
  const float* key_  = (const float*)d_in[1];
  const float* value = (const float*)d_in[2];
  const float* Wq = (const float*)d_in[3];
  const float* Wk = (const float*)d_in[4];
  const float* Wv = (const float*)d_in[5];
  const float* Wo = (const float*)d_in[6];
  const float* bq = (const float*)d_in[7];
  const float* bk = (const float*)d_in[8];
  const float* bv = (const float*)d_in[9];
  const float* bo = (const float*)d_in[10];
  const float* Er = (const float*)d_in[11];

  char* p = (char*)d_ws;
  size_t off = 0;
  auto alloc = [&](size_t bytes) {
    char* r = p + off;
    off += (bytes + 255) & ~(size_t)255;
    return r;
  };
  u16* Xq  = (u16*)alloc((size_t)2048 * 1024 * 2);
  u16* Xk  = (u16*)alloc((size_t)2048 * 1024 * 2);
  u16* Xv  = (u16*)alloc((size_t)2048 * 1024 * 2);
  u16* Wqb = (u16*)alloc((size_t)1024 * 1024 * 2);
  u16* Wkb = (u16*)alloc((size_t)1024 * 1024 * 2);
  u16* Wvb = (u16*)alloc((size_t)1024 * 1024 * 2);
  u16* Wob = (u16*)alloc((size_t)1024 * 1024 * 2);
  u16* Erb = (u16*)alloc((size_t)2048 * 64 * 2);   // 2047 rows used + 1 zeroed spare
  u16* qh  = (u16*)alloc((size_t)2048 * 1024 * 2); // [b,h,s,d]
  u16* kh  = (u16*)alloc((size_t)2048 * 1024 * 2); // [b,h,s,d]
  u16* vt  = (u16*)alloc((size_t)2048 * 1024 * 2); // [b,h,d,s]
  u16* attnb = (u16*)alloc((size_t)2048 * 1024 * 2);

  CvtArgs ca;
  ca.j[0] = {query, Xq, 2048 * 1024};
  ca.j[1] = {key_,  Xk, 2048 * 1024};
  ca.j[2] = {value, Xv, 2048 * 1024};
  ca.j[3] = {Wq, Wqb, 1024 * 1024};
  ca.j[4] = {Wk, Wkb, 1024 * 1024};
  ca.j[5] = {Wv, Wvb, 1024 * 1024};
  ca.j[6] = {Wo, Wob, 1024 * 1024};
  ca.j[7] = {Er, Erb, 2047 * 64};
  cvt_kernel<<<dim3(2048, 8, 1), 256, 0, stream>>>(ca);
  // zero the spare Er row (row 2047) so the T-window MFMA never reads poison
  hipMemsetAsync(Erb + (size_t)2047 * 64, 0, 64 * sizeof(u16), stream);

  // Q, K projections -> head-split bf16
  GemmJobs gp;
  gp.p[0] = {Xq, Wqb, bq, (void*)qh};
  gp.p[1] = {Xk, Wkb, bk, (void*)kh};
  gp.p[2] = gp.p[0];
  gemm_bt<0><<<dim3(8, 16, 2), 256, 0, stream>>>(gp, 1024);

  // V projection with swapped operands -> V^T [bh][d][s] directly
  GemmJobs gv;
  gv.p[0] = {Wvb, Xv, bv, (void*)vt};
  gv.p[1] = gv.p[0];
  gv.p[2] = gv.p[0];
  gemm_bt<2><<<dim3(16, 8, 1), 256, 0, stream>>>(gv, 1024);

  attn_rel<<<dim3(2048, 1, 1), 128, 0, stream>>>(qh, kh, vt, Erb, attnb);

  GemmJobs go;
  go.p[0] = {attnb, Wob, bo, d_out};
  go.p[1] = go.p[0];
  go.p[2] = go.p[0];
  gemm_bt<1><<<dim3(8, 16, 1), 256, 0, stream>>>(go, 1024);
}

// Round 3
// 106.207 us; speedup vs baseline: 1.7905x; 1.7905x over previous
//
#include <hip/hip_runtime.h>
#include <hip/hip_bf16.h>
#include <cstdint>
#include <cstddef>

typedef __attribute__((ext_vector_type(8))) short bf16x8;
typedef __attribute__((ext_vector_type(4))) float f32x4;
typedef unsigned short u16;
typedef unsigned int u32;

#define DEV static __device__ __forceinline__

constexpr int Sc = 1024, DMc = 1024, Hc = 16, DKc = 64;

DEV u16 f2bf(float f) {
  u32 u = __float_as_uint(f);
  return (u16)((u + 0x7FFFu + ((u >> 16) & 1u)) >> 16);
}
DEV float bf2f(u16 h) { return __uint_as_float(((u32)h) << 16); }

DEV void lds_fence() {
  asm volatile("s_waitcnt lgkmcnt(0)" ::: "memory");
  __builtin_amdgcn_sched_barrier(0);
}

// async global->LDS: 16B/lane, LDS dest = wave-uniform base + lane*16
#define GLDS16(g, l)                                                        \
  __builtin_amdgcn_global_load_lds(                                         \
      (const __attribute__((address_space(1))) void*)(g),                   \
      (__attribute__((address_space(3))) void*)(l), 16, 0, 0)

// ---------------- f32 -> bf16 + chunk-swizzle conversion ----------------
// Output layout: within each 64-elem (128B) block, 16B chunk c stored at
// c ^ (row & 7).  rsh = log2(chunks per row).
struct CvtJob { const float* in; u16* out; int nchunk; int rsh; };
struct CvtArgs { CvtJob j[8]; };

__global__ __launch_bounds__(256) void cvt_kernel(CvtArgs a) {
  CvtJob job = a.j[blockIdx.y];
  int ci = (int)(blockIdx.x * 256 + threadIdx.x);
  if (ci >= job.nchunk) return;
  const float* src = job.in + (size_t)ci * 8;
  float4 v0 = *(const float4*)src;
  float4 v1 = *(const float4*)(src + 4);
  bf16x8 o;
  o[0] = (short)f2bf(v0.x); o[1] = (short)f2bf(v0.y);
  o[2] = (short)f2bf(v0.z); o[3] = (short)f2bf(v0.w);
  o[4] = (short)f2bf(v1.x); o[5] = (short)f2bf(v1.y);
  o[6] = (short)f2bf(v1.z); o[7] = (short)f2bf(v1.w);
  int row = ci >> job.rsh;
  int co = (ci & ~7) | ((ci & 7) ^ (row & 7));
  *(bf16x8*)(job.out + (size_t)co * 8) = o;
}

// ---------------- GEMM: C = A(MxK) * W(NxK)^T + bias ----------------
// All global bf16 operands are chunk-swizzled (key row&7).
// MODE 0 (BM=128): flat grid 384. id<256: z=id>>7 (Q,K) -> bf16 head-split
//   swizzled qh/kh. id>=256: z=2 (A=Wv, W=Xv) -> bf16 swizzled vt[bh][d][s].
// MODE 1 (BM=64): out-proj, grid 256 (8 n-blk x 32 m-blk), f32 out (plain).
struct GemmJob { const u16* A; const u16* W; const float* bias; void* out; };
struct GemmArgs { GemmJob p[3]; };

template<int BM, int MODE>
__global__ __launch_bounds__(256, 2) void gemm_bt(GemmArgs G) {
  constexpr int MI = BM / 32;
  __shared__ __align__(16) u16 sA[2][BM * 64];
  __shared__ __align__(16) u16 sB[2][128 * 64];
  const int tid = threadIdx.x, lane = tid & 63, w = tid >> 6;
  const int cl = lane & 15, rg = lane >> 4;
  const int srow = lane >> 3, schk = lane & 7;
  int z, m0, n0;
  if (MODE == 0) {
    int id = blockIdx.x;
    if (id < 256) { z = id >> 7; int r = id & 127; m0 = (r >> 3) * 128; n0 = (r & 7) * 128; }
    else          { z = 2;       int r = id - 256; m0 = (r >> 4) * 128; n0 = (r & 15) * 128; }
  } else {
    z = 0; int id = blockIdx.x; m0 = (id >> 3) * 64; n0 = (id & 7) * 128;
  }
  GemmJob P = G.p[z];
  constexpr int K = 1024;
  const int wm = (w >> 1) * (MI * 16), wn = (w & 1) * 64;
  f32x4 acc[MI][4] = {};

  auto stage = [&](int kt, int b) {
    const u16* Ab = P.A + (size_t)m0 * K + kt * 64;
    const u16* Wb = P.W + (size_t)n0 * K + kt * 64;
    #pragma unroll
    for (int i = 0; i < BM / 32; ++i)
      GLDS16(Ab + (size_t)(i * 32 + w * 8 + srow) * K + schk * 8, &sA[b][(i * 32 + w * 8) * 64]);
    #pragma unroll
    for (int i = 0; i < 4; ++i)
      GLDS16(Wb + (size_t)(i * 32 + w * 8 + srow) * K + schk * 8, &sB[b][(i * 32 + w * 8) * 64]);
  };

  stage(0, 0);
  for (int kt = 0; kt < 16; ++kt) {
    __syncthreads();
    if (kt < 15) stage(kt + 1, (kt + 1) & 1);
    const u16* A_ = sA[kt & 1];
    const u16* B_ = sB[kt & 1];
    #pragma unroll
    for (int kk = 0; kk < 2; ++kk) {
      bf16x8 af[MI], bfr[4];
      #pragma unroll
      for (int mi = 0; mi < MI; ++mi) {
        int row = wm + mi * 16 + cl;
        af[mi] = *(const bf16x8*)(A_ + row * 64 + ((kk * 4 + rg) ^ (row & 7)) * 8);
      }
      #pragma unroll
      for (int ni = 0; ni < 4; ++ni) {
        int row = wn + ni * 16 + cl;
        bfr[ni] = *(const bf16x8*)(B_ + row * 64 + ((kk * 4 + rg) ^ (row & 7)) * 8);
      }
      #pragma unroll
      for (int mi = 0; mi < MI; ++mi)
        #pragma unroll
        for (int ni = 0; ni < 4; ++ni)
          acc[mi][ni] = __builtin_amdgcn_mfma_f32_16x16x32_bf16(af[mi], bfr[ni], acc[mi][ni], 0, 0, 0);
    }
  }
  #pragma unroll
  for (int mi = 0; mi < MI; ++mi) {
    #pragma unroll
    for (int ni = 0; ni < 4; ++ni) {
      #pragma unroll
      for (int j = 0; j < 4; ++j) {
        int m = m0 + wm + mi * 16 + rg * 4 + j;
        int n = n0 + wn + ni * 16 + cl;
        if (MODE == 1) {
          ((float*)P.out)[(size_t)m * DMc + n] = acc[mi][ni][j] + P.bias[n];
        } else if (z < 2) {
          float v = acc[mi][ni][j] + P.bias[n];
          int h = n >> 6, d = n & 63;
          int c2 = (d >> 3) ^ (m & 7);
          ((u16*)P.out)[((size_t)((m >> 10) * Hc + h) * Sc + (m & 1023)) * DKc + c2 * 8 + (d & 7)] = f2bf(v);
        } else {
          float v = acc[mi][ni][j] + P.bias[m];
          int d = m & 63, h = m >> 6, bb = n >> 10, s = n & 1023;
          int c2 = ((s & 63) >> 3) ^ (d & 7);
          ((u16*)P.out)[((size_t)(bb * Hc + h) * DKc + d) * Sc + (s & ~63) + c2 * 8 + (s & 7)] = f2bf(v);
        }
      }
    }
  }
}

// ---------------- fused relative attention ----------------
// grid 512 (bh = id&31, qt = id>>5), 256 thr (4 waves x 16 q-rows).
// K,V LDS double-buffered via global_load_lds; Er fragments direct (L2-hot).
// No online max (scores bounded ~|6|); l-reduce deferred to epilogue.
__global__ __launch_bounds__(256, 2) void attn_rel(
    const u16* __restrict__ qg, const u16* __restrict__ kg,
    const u16* __restrict__ vtg, const u16* __restrict__ erg,
    u16* __restrict__ og) {
  __shared__ __align__(16) u16 sK[2][64 * 64];
  __shared__ __align__(16) u16 sV[2][64 * 64];
  __shared__ __align__(16) u16 sT[4][16 * 80];
  __shared__ __align__(16) u16 sP[4][16 * 72];
  const int tid = threadIdx.x, lane = tid & 63, w = tid >> 6;
  const int cl = lane & 15, rg = lane >> 4;
  const int key = cl & 7;
  const int bh = blockIdx.x & 31, qt = blockIdx.x >> 5, q0 = qt * 64;

  const u16* qrow = qg + ((size_t)bh * Sc + q0 + w * 16 + cl) * DKc;
  bf16x8 qf0 = *(const bf16x8*)(qrow + (rg ^ key) * 8);
  bf16x8 qf1 = *(const bf16x8*)(qrow + ((rg + 4) ^ key) * 8);
  f32x4 oacc[4] = {};
  float lrow[4] = {0.f, 0.f, 0.f, 0.f};
  u16* Tw = sT[w];
  u16* Pw = sP[w];
  const u16* kbase = kg + (size_t)bh * Sc * DKc;
  const u16* vbase = vtg + (size_t)bh * DKc * Sc;

  auto stage = [&](int t, int b) {
    const u16* ks = kbase + t * 64 * 64;
    #pragma unroll
    for (int i = 0; i < 2; ++i) {
      GLDS16(ks + (i * 32 + w * 8) * 64 + lane * 8, &sK[b][(i * 32 + w * 8) * 64]);
      GLDS16(vbase + (size_t)(i * 32 + w * 8 + (lane >> 3)) * Sc + t * 64 + (lane & 7) * 8,
             &sV[b][(i * 32 + w * 8) * 64]);
    }
  };

  stage(0, 0);
  for (int t = 0; t < 16; ++t) {
    __syncthreads();
    if (t < 15) stage(t + 1, (t + 1) & 1);
    const u16* Kb = sK[t & 1];
    const u16* Vb = sV[t & 1];
    const u16* ebase = erg + (size_t)(q0 - t * 64 + 960) * DKc;

    f32x4 sc4[4];
    #pragma unroll
    for (int nc = 0; nc < 4; ++nc) {
      const u16* kr = Kb + (nc * 16 + cl) * 64;
      bf16x8 b0 = *(const bf16x8*)(kr + (rg ^ key) * 8);
      bf16x8 b1 = *(const bf16x8*)(kr + ((rg + 4) ^ key) * 8);
      f32x4 a = {};
      a = __builtin_amdgcn_mfma_f32_16x16x32_bf16(qf0, b0, a, 0, 0, 0);
      a = __builtin_amdgcn_mfma_f32_16x16x32_bf16(qf1, b1, a, 0, 0, 0);
      sc4[nc] = a;
    }
    // T = Q . Er_window^T  (wave-local columns rc0*16+cl, window 79 wide)
    #pragma unroll
    for (int rc0 = 0; rc0 < 5; ++rc0) {
      const u16* er = ebase + (size_t)((w + rc0) * 16 + cl) * DKc;
      bf16x8 b0 = *(const bf16x8*)(er + (rg ^ key) * 8);
      bf16x8 b1 = *(const bf16x8*)(er + ((rg + 4) ^ key) * 8);
      f32x4 a = {};
      a = __builtin_amdgcn_mfma_f32_16x16x32_bf16(qf0, b0, a, 0, 0, 0);
      a = __builtin_amdgcn_mfma_f32_16x16x32_bf16(qf1, b1, a, 0, 0, 0);
      #pragma unroll
      for (int j = 0; j < 4; ++j)
        Tw[(rg * 4 + j) * 80 + rc0 * 16 + cl] = f2bf(a[j]);
    }
    lds_fence();
    #pragma unroll
    for (int j = 0; j < 4; ++j) {
      const int qi = rg * 4 + j;
      #pragma unroll
      for (int nc = 0; nc < 4; ++nc) {
        int rl = qi + 63 - (nc * 16 + cl);  // wave-local, in [0,78]
        float p = __expf((sc4[nc][j] + bf2f(Tw[qi * 80 + rl])) * 0.125f);
        lrow[j] += p;
        Pw[qi * 72 + nc * 16 + cl] = f2bf(p);
      }
    }
    lds_fence();
    bf16x8 pa0 = *(const bf16x8*)(Pw + cl * 72 + rg * 8);
    bf16x8 pa1 = *(const bf16x8*)(Pw + cl * 72 + 32 + rg * 8);
    #pragma unroll
    for (int dc = 0; dc < 4; ++dc) {
      const u16* vr = Vb + (dc * 16 + cl) * 64;
      bf16x8 b0 = *(const bf16x8*)(vr + (rg ^ key) * 8);
      bf16x8 b1 = *(const bf16x8*)(vr + ((rg + 4) ^ key) * 8);
      oacc[dc] = __builtin_amdgcn_mfma_f32_16x16x32_bf16(pa0, b0, oacc[dc], 0, 0, 0);
      oacc[dc] = __builtin_amdgcn_mfma_f32_16x16x32_bf16(pa1, b1, oacc[dc], 0, 0, 0);
    }
  }
  // deferred l reduce (once): sum across the 16 cl lanes
  #pragma unroll
  for (int j = 0; j < 4; ++j) {
    float l = lrow[j];
    #pragma unroll
    for (int off = 1; off < 16; off <<= 1) l += __shfl_xor(l, off);
    lrow[j] = l;
  }
  const int b_ = bh >> 4, h = bh & 15;
  #pragma unroll
  for (int dc = 0; dc < 4; ++dc) {
    #pragma unroll
    for (int j = 0; j < 4; ++j) {
      int qr = q0 + w * 16 + rg * 4 + j;
      float v = oacc[dc][j] / lrow[j];
      int col = dc * 16 + cl;
      int c2 = (col >> 3) ^ (qr & 7);
      og[((size_t)(b_ * Sc + qr)) * DMc + h * 64 + c2 * 8 + (col & 7)] = f2bf(v);
    }
  }
}

// ---------------- host ----------------
extern "C" void kernel_launch(void* const* d_in, const int* in_sizes, int n_in,
                              void* d_out, int out_size, void* d_ws, size_t ws_size,
                              hipStream_t stream) {
  (void)in_sizes; (void)n_in; (void)out_size; (void)ws_size;
  const float* query = (const float*)d_in[0];
  const float* key_  = (const float*)d_in[1];
  const float* value = (const float*)d_in[2];
  const float* Wq = (const float*)d_in[3];
  const float* Wk = (const float*)d_in[4];
  const float* Wv = (const float*)d_in[5];
  const float* Wo = (const float*)d_in[6];
  const float* bq = (const float*)d_in[7];
  const float* bk = (const float*)d_in[8];
  const float* bv = (const float*)d_in[9];
  const float* bo = (const float*)d_in[10];
  const float* Er = (const float*)d_in[11];

  char* p = (char*)d_ws;
  size_t off = 0;
  auto alloc = [&](size_t bytes) {
    char* r = p + off;
    off += (bytes + 255) & ~(size_t)255;
    return r;
  };
  u16* Xq  = (u16*)alloc((size_t)2048 * 1024 * 2);
  u16* Xk  = (u16*)alloc((size_t)2048 * 1024 * 2);
  u16* Xv  = (u16*)alloc((size_t)2048 * 1024 * 2);
  u16* Wqb = (u16*)alloc((size_t)1024 * 1024 * 2);
  u16* Wkb = (u16*)alloc((size_t)1024 * 1024 * 2);
  u16* Wvb = (u16*)alloc((size_t)1024 * 1024 * 2);
  u16* Wob = (u16*)alloc((size_t)1024 * 1024 * 2);
  u16* Erb = (u16*)alloc((size_t)2048 * 64 * 2);
  u16* qh  = (u16*)alloc((size_t)2048 * 1024 * 2); // [bh][s][64] swz
  u16* kh  = (u16*)alloc((size_t)2048 * 1024 * 2); // [bh][s][64] swz
  u16* vt  = (u16*)alloc((size_t)2048 * 1024 * 2); // [bh][64][s] swz
  u16* attnb = (u16*)alloc((size_t)2048 * 1024 * 2); // [m][1024] swz

  CvtArgs ca;
  ca.j[0] = {query, Xq, 262144, 7};
  ca.j[1] = {key_,  Xk, 262144, 7};
  ca.j[2] = {value, Xv, 262144, 7};
  ca.j[3] = {Wq, Wqb, 131072, 7};
  ca.j[4] = {Wk, Wkb, 131072, 7};
  ca.j[5] = {Wv, Wvb, 131072, 7};
  ca.j[6] = {Wo, Wob, 131072, 7};
  ca.j[7] = {Er, Erb, 16376, 3};
  cvt_kernel<<<dim3(1024, 8, 1), 256, 0, stream>>>(ca);
  hipMemsetAsync(Erb + (size_t)2047 * 64, 0, 64 * sizeof(u16), stream);

  GemmArgs gp;
  gp.p[0] = {Xq, Wqb, bq, (void*)qh};
  gp.p[1] = {Xk, Wkb, bk, (void*)kh};
  gp.p[2] = {Wvb, Xv, bv, (void*)vt};
  gemm_bt<128, 0><<<dim3(384, 1, 1), 256, 0, stream>>>(gp);

  attn_rel<<<dim3(512, 1, 1), 256, 0, stream>>>(qh, kh, vt, Erb, attnb);

  GemmArgs go;
  go.p[0] = {attnb, Wob, bo, d_out};
  go.p[1] = go.p[0];
  go.p[2] = go.p[0];
  gemm_bt<64, 1><<<dim3(256, 1, 1), 256, 0, stream>>>(go);
}